// Round 7
// baseline (93.707 us; speedup 1.0000x reference)
//
#include <hip/hip_runtime.h>
#include <hip/hip_bf16.h>

#define B_DIM 32
#define T_DIM 2048
#define D_DIM 1024
#define S_MAXK 32
#define NCHUNK 8
#define TCH 256            // T_DIM / NCHUNK
#define DS  512            // D_DIM / 2 (two d-slices per chunk)

// ws layout (bytes), all zero-memset each call:
//   hsum   float[B][32][D] @ 0       : 4,194,304  (raw sums, atomically accumulated)
//   counts uint [B][32]    @ 4194304 : 4,096
//   posneg uint [B][32]    @ 4198400 : 4,096      (0xFFFFFFFF - firstpos; 0 = absent)
//   ctrl   {float tot, float num, uint done} @ 4202496
#define HSUM_OFF 0
#define CNT_OFF  4194304
#define PNEG_OFF 4198400
#define CTRL_OFF 4202496
#define WS_ZERO  (4202496 + 256)

// Sequential-scan binning: block = (b, t-chunk, d-half). Thread owns one
// float2 column; t iterated linearly with 8-deep named-register load batches;
// |v| added into LDS acc[step][col] (wave-uniform step -> non-atomic RMW,
// 2-way bank aliasing = free). x is read in pure ascending address order.
__global__ __launch_bounds__(256) void k_seq(const float* __restrict__ x,
                                             const int* __restrict__ sid,
                                             float* __restrict__ hsum,
                                             unsigned* __restrict__ counts,
                                             unsigned* __restrict__ posneg) {
    __shared__ float acc[S_MAXK * DS];   // 64 KB
    __shared__ int   sc[TCH];

    const int blk = blockIdx.x;
    const int b   = blk >> 4;
    const int c   = (blk >> 1) & (NCHUNK - 1);
    const int sl  = blk & 1;
    const int tid = threadIdx.x;

    float4* az = (float4*)acc;
    #pragma unroll
    for (int i = tid; i < S_MAXK * DS / 4; i += 256)
        az[i] = make_float4(0.f, 0.f, 0.f, 0.f);
    sc[tid] = sid[b * T_DIM + c * TCH + tid];
    __syncthreads();

    // counts + first-pos for this chunk (d-slice 0 only; 32 lanes of wave 0)
    if (sl == 0 && tid < 32) {
        int cnt = 0, first = -1;
        for (int t = 0; t < TCH; ++t) {
            if (sc[t] == tid + 1) { cnt++; if (first < 0) first = t; }
        }
        if (cnt) {
            atomicAdd(&counts[(b << 5) + tid], (unsigned)cnt);
            atomicMax(&posneg[(b << 5) + tid],
                      0xFFFFFFFFu - (unsigned)(c * TCH + first));
        }
    }

    const float2* xp = (const float2*)(x + (size_t)b * T_DIM * D_DIM
                                         + (size_t)c * TCH * D_DIM + sl * DS);
    float2* accp = (float2*)acc;         // bin stride DS/2 = 256 float2

    for (int t = 0; t < TCH; t += 8) {
        float2 v0 = xp[(size_t)(t + 0) * (D_DIM / 2) + tid];
        float2 v1 = xp[(size_t)(t + 1) * (D_DIM / 2) + tid];
        float2 v2 = xp[(size_t)(t + 2) * (D_DIM / 2) + tid];
        float2 v3 = xp[(size_t)(t + 3) * (D_DIM / 2) + tid];
        float2 v4 = xp[(size_t)(t + 4) * (D_DIM / 2) + tid];
        float2 v5 = xp[(size_t)(t + 5) * (D_DIM / 2) + tid];
        float2 v6 = xp[(size_t)(t + 6) * (D_DIM / 2) + tid];
        float2 v7 = xp[(size_t)(t + 7) * (D_DIM / 2) + tid];
        int s0 = sc[t + 0], s1 = sc[t + 1], s2 = sc[t + 2], s3 = sc[t + 3];
        int s4 = sc[t + 4], s5 = sc[t + 5], s6 = sc[t + 6], s7 = sc[t + 7];
        if (s0) { float2 a = accp[(s0 - 1) * 256 + tid];
                  a.x += fabsf(v0.x); a.y += fabsf(v0.y);
                  accp[(s0 - 1) * 256 + tid] = a; }
        if (s1) { float2 a = accp[(s1 - 1) * 256 + tid];
                  a.x += fabsf(v1.x); a.y += fabsf(v1.y);
                  accp[(s1 - 1) * 256 + tid] = a; }
        if (s2) { float2 a = accp[(s2 - 1) * 256 + tid];
                  a.x += fabsf(v2.x); a.y += fabsf(v2.y);
                  accp[(s2 - 1) * 256 + tid] = a; }
        if (s3) { float2 a = accp[(s3 - 1) * 256 + tid];
                  a.x += fabsf(v3.x); a.y += fabsf(v3.y);
                  accp[(s3 - 1) * 256 + tid] = a; }
        if (s4) { float2 a = accp[(s4 - 1) * 256 + tid];
                  a.x += fabsf(v4.x); a.y += fabsf(v4.y);
                  accp[(s4 - 1) * 256 + tid] = a; }
        if (s5) { float2 a = accp[(s5 - 1) * 256 + tid];
                  a.x += fabsf(v5.x); a.y += fabsf(v5.y);
                  accp[(s5 - 1) * 256 + tid] = a; }
        if (s6) { float2 a = accp[(s6 - 1) * 256 + tid];
                  a.x += fabsf(v6.x); a.y += fabsf(v6.y);
                  accp[(s6 - 1) * 256 + tid] = a; }
        if (s7) { float2 a = accp[(s7 - 1) * 256 + tid];
                  a.x += fabsf(v7.x); a.y += fabsf(v7.y);
                  accp[(s7 - 1) * 256 + tid] = a; }
    }
    __syncthreads();

    // flush 64KB of partial sums via fp32 atomics (coalesced, distinct addrs)
    float* hb = hsum + ((size_t)(b << 5)) * D_DIM + sl * DS;
    for (int i = tid; i < S_MAXK * DS; i += 256) {
        int s = i >> 9;           // / DS
        int d = i & (DS - 1);
        atomicAdd(&hb[(size_t)s * D_DIM + d], acc[i]);
    }
}

// One block per b: argsort pos, pairwise E (on sums * 1/count), per-b loss;
// atomic-accumulate into ctrl; last block writes out = tot/(num+1e-9).
__global__ __launch_bounds__(256) void k_pairs(const float* __restrict__ hsum,
                                               const unsigned* __restrict__ counts,
                                               const unsigned* __restrict__ posneg,
                                               const int* __restrict__ labels,
                                               float* __restrict__ ctrl,
                                               float* __restrict__ out) {
    const int b = blockIdx.x;
    const int tid = threadIdx.x;
    __shared__ unsigned posl[32];
    __shared__ float    rcp[32];
    __shared__ int      ordl[32];
    __shared__ float    El[31];

    if (tid < 32) {
        posl[tid] = 0xFFFFFFFFu - posneg[(b << 5) + tid];  // absent -> 0xFFFFFFFF
        unsigned cc = counts[(b << 5) + tid];
        rcp[tid] = 1.0f / (float)(cc > 1u ? cc : 1u);
    }
    __syncthreads();
    if (tid < 32) {                         // stable argsort of pos
        unsigned ps = posl[tid];
        int rk = 0;
        for (int j = 0; j < 32; ++j) {
            unsigned pj = posl[j];
            if (pj < ps || (pj == ps && j < tid)) rk++;
        }
        ordl[rk] = tid;
    }
    __syncthreads();

    const int wave = tid >> 6;
    const int lane = tid & 63;
    for (int p = wave; p < 31; p += 4) {
        int A  = ordl[p];
        int B2 = ordl[p + 1];
        float ssum = 0.0f;
        if (posl[B2] < (unsigned)T_DIM) {
            const float* pa = &hsum[((size_t)(b << 5) + A)  * D_DIM];
            const float* pb = &hsum[((size_t)(b << 5) + B2) * D_DIM];
            float ra = rcp[A], rb = rcp[B2];
            for (int d = lane * 4; d < D_DIM; d += 256) {
                float4 a4 = *(const float4*)(pa + d);
                float4 b4 = *(const float4*)(pb + d);
                float d0 = fmaxf(a4.x * ra - b4.x * rb, 0.f);
                float d1 = fmaxf(a4.y * ra - b4.y * rb, 0.f);
                float d2 = fmaxf(a4.z * ra - b4.z * rb, 0.f);
                float d3 = fmaxf(a4.w * ra - b4.w * rb, 0.f);
                ssum += d0 * d0 + d1 * d1 + d2 * d2 + d3 * d3;
            }
        }
        #pragma unroll
        for (int off = 32; off; off >>= 1) ssum += __shfl_down(ssum, off);
        if (lane == 0) El[p] = ssum * (1.0f / D_DIM);
    }
    __syncthreads();

    if (tid == 0) {
        float lpos = 0.f, lneg = 0.f;
        int np = 0, ni = 0, nn = 0;
        for (int s2 = 0; s2 < 32; ++s2) nn += (posl[s2] < (unsigned)T_DIM) ? 1 : 0;
        for (int p = 0; p < 31; ++p) {
            int A  = ordl[p];
            int B2 = ordl[p + 1];
            if (posl[B2] < (unsigned)T_DIM) {    // pair_valid
                float Ev = El[p];
                np++; lpos += Ev;
                if (A > B2) { ni++; lneg += fmaxf(1.0f - Ev, 0.0f); }  // ALPHA=1
            }
        }
        float loss_pos = lpos / (float)(np > 1 ? np : 1);
        float loss_neg = lneg / (float)(ni > 1 ? ni : 1);
        int lab = labels[b];
        bool pc = (lab == 1) && (nn >= 2);
        bool nc = (lab == 0) && (ni > 0);
        float contrib = (pc ? loss_pos : 0.0f) + (nc ? loss_neg : 0.0f);
        float cf = (float)((pc ? 1 : 0) + (nc ? 1 : 0));

        atomicAdd(&ctrl[0], contrib);
        atomicAdd(&ctrl[1], cf);
        __threadfence();
        unsigned old = atomicAdd(&((unsigned*)ctrl)[2], 1u);
        if (old == (unsigned)(B_DIM - 1)) {      // last block overall
            __threadfence();
            float tot = atomicAdd(&ctrl[0], 0.0f);   // coherent reads
            float num = atomicAdd(&ctrl[1], 0.0f);
            out[0] = tot / (num + 1e-9f);
        }
    }
}

extern "C" void kernel_launch(void* const* d_in, const int* in_sizes, int n_in,
                              void* d_out, int out_size, void* d_ws, size_t ws_size,
                              hipStream_t stream) {
    const float* x      = (const float*)d_in[0];
    const int*   sid    = (const int*)d_in[1];
    const int*   labels = (const int*)d_in[2];
    float* out = (float*)d_out;
    char*  ws  = (char*)d_ws;

    float*    hsum   = (float*)(ws + HSUM_OFF);
    unsigned* counts = (unsigned*)(ws + CNT_OFF);
    unsigned* posneg = (unsigned*)(ws + PNEG_OFF);
    float*    ctrl   = (float*)(ws + CTRL_OFF);

    hipMemsetAsync(ws, 0, WS_ZERO, stream);   // hsum + counts + posneg + ctrl

    k_seq  <<<B_DIM * NCHUNK * 2, 256, 0, stream>>>(x, sid, hsum, counts, posneg);
    k_pairs<<<B_DIM,              256, 0, stream>>>(hsum, counts, posneg, labels, ctrl, out);
}